// Round 4
// baseline (76.012 us; speedup 1.0000x reference)
//
#include <hip/hip_runtime.h>
#include <math.h>

// Tropical max/min-plus pseudo-matmul.
// out[b,u] = max_f(x[b,f] + w[f,u]) for u<128, min_f otherwise.
//
// R3 lesson: launch_bounds(512,8) capped VGPRs at 64 -> likely spill; and
// per-iter s_load/vmem waits serialize. This round: VGPR cap 128 (bounds 512,4),
// software-pipelined w (A/B reg buffers), wave = 8 rows x 128 u (dwordx2 w),
// full K covered in-block (8 waves x 64k), LDS combine of 8 partials.
// VALU floor: 268M adds*1.5/64 lanes * 2cyc = 12.3k cyc/SIMD ~= 5.1 us.

#define FEAT  512
#define UNITS 256
#define R     8     // rows per block
#define KW    64    // k per wave
#define NW    8     // waves per block

template<bool IS_MAX>
__device__ __forceinline__ float tmerge(float a, float b) {
    return IS_MAX ? fmaxf(a, b) : fminf(a, b);
}

template<bool IS_MAX>
__device__ __forceinline__ void oct_compute(const float* __restrict__ xp, int oct,
                                            const float2* __restrict__ wb,
                                            float2* __restrict__ acc) {
    #pragma unroll
    for (int r = 0; r < R; ++r) {
        // wave-uniform addresses -> scalar loads (x streamed through K$)
        const float4 a0 = *(const float4*)(xp + (size_t)r * FEAT + oct * 8);
        const float4 a1 = *(const float4*)(xp + (size_t)r * FEAT + oct * 8 + 4);
        float2 A = acc[r];
        A.x = tmerge<IS_MAX>(tmerge<IS_MAX>(A.x, a0.x + wb[0].x), a0.y + wb[1].x);
        A.x = tmerge<IS_MAX>(tmerge<IS_MAX>(A.x, a0.z + wb[2].x), a0.w + wb[3].x);
        A.x = tmerge<IS_MAX>(tmerge<IS_MAX>(A.x, a1.x + wb[4].x), a1.y + wb[5].x);
        A.x = tmerge<IS_MAX>(tmerge<IS_MAX>(A.x, a1.z + wb[6].x), a1.w + wb[7].x);
        A.y = tmerge<IS_MAX>(tmerge<IS_MAX>(A.y, a0.x + wb[0].y), a0.y + wb[1].y);
        A.y = tmerge<IS_MAX>(tmerge<IS_MAX>(A.y, a0.z + wb[2].y), a0.w + wb[3].y);
        A.y = tmerge<IS_MAX>(tmerge<IS_MAX>(A.y, a1.x + wb[4].y), a1.y + wb[5].y);
        A.y = tmerge<IS_MAX>(tmerge<IS_MAX>(A.y, a1.z + wb[6].y), a1.w + wb[7].y);
        acc[r] = A;
    }
}

template<bool IS_MAX>
__device__ __forceinline__ void trop_body(const float* __restrict__ x,
                                          const float* __restrict__ w,
                                          float* __restrict__ out,
                                          int ubase, float* __restrict__ part) {
    const int tid  = threadIdx.x;
    const int lane = tid & 63;
    const int wv   = __builtin_amdgcn_readfirstlane(tid >> 6);  // 0..7, SGPR
    const int u    = ubase + lane * 2;
    const int row0 = blockIdx.y * R;
    const int kb   = wv * KW;

    const float* wp = w + (size_t)kb * UNITS + u;      // lane-strided, 512B/load
    const float* xp = x + (size_t)row0 * FEAT + kb;    // wave-uniform

    float2 acc[R];
    const float init = IS_MAX ? -__builtin_inff() : __builtin_inff();
    #pragma unroll
    for (int r = 0; r < R; ++r) acc[r] = make_float2(init, init);

    // software pipeline: A/B register buffers for w octets
    float2 wA[8], wB[8];
    #pragma unroll
    for (int k = 0; k < 8; ++k) wA[k] = *(const float2*)(wp + (size_t)k * UNITS);

    #pragma unroll
    for (int oct = 0; oct < KW / 8; oct += 2) {
        #pragma unroll
        for (int k = 0; k < 8; ++k)
            wB[k] = *(const float2*)(wp + (size_t)((oct + 1) * 8 + k) * UNITS);
        oct_compute<IS_MAX>(xp, oct, wA, acc);
        if (oct + 2 < KW / 8) {
            #pragma unroll
            for (int k = 0; k < 8; ++k)
                wA[k] = *(const float2*)(wp + (size_t)((oct + 2) * 8 + k) * UNITS);
        }
        oct_compute<IS_MAX>(xp, oct + 1, wB, acc);
    }

    // ---- combine 8 k-partials via LDS (32 KB) ----
    #pragma unroll
    for (int r = 0; r < R; ++r)
        *(float2*)&part[(wv * R + r) * 128 + lane * 2] = acc[r];
    __syncthreads();

    // wave wv reduces row r == wv; float2 reads, 2-way bank alias (free)
    float2 v = *(const float2*)&part[(size_t)(0 * R + wv) * 128 + lane * 2];
    #pragma unroll
    for (int j = 1; j < NW; ++j) {
        const float2 p = *(const float2*)&part[(size_t)(j * R + wv) * 128 + lane * 2];
        v.x = tmerge<IS_MAX>(v.x, p.x);
        v.y = tmerge<IS_MAX>(v.y, p.y);
    }
    *(float2*)&out[(size_t)(row0 + wv) * UNITS + u] = v;  // 512B coalesced
}

__global__ __launch_bounds__(512, 4) void tropical_kernel(const float* __restrict__ x,
                                                          const float* __restrict__ w,
                                                          float* __restrict__ out) {
    __shared__ float part[NW * R * 128];       // 32 KB
    const int ubase = blockIdx.x * 128;        // 0 -> max half; 128 -> min half
    if (ubase < 128) trop_body<true>(x, w, out, ubase, part);
    else             trop_body<false>(x, w, out, ubase, part);
}

extern "C" void kernel_launch(void* const* d_in, const int* in_sizes, int n_in,
                              void* d_out, int out_size, void* d_ws, size_t ws_size,
                              hipStream_t stream) {
    const float* x = (const float*)d_in[0];   // (2048, 512)
    const float* w = (const float*)d_in[1];   // (512, 256)
    float* out = (float*)d_out;               // (2048, 256)

    // 2 u-halves x 256 row-groups = 512 blocks x 8 waves = 4096 waves (2 blk/CU)
    dim3 grid(UNITS / 128, 2048 / R);
    tropical_kernel<<<grid, dim3(512), 0, stream>>>(x, w, out);
}